// Round 10
// baseline (254.544 us; speedup 1.0000x reference)
//
#include <hip/hip_runtime.h>
#include <math.h>

// DiffDispatchLP: batched (256x) PDHG, 400 iters.
// R10: R9 + the entire PDHG-loop arithmetic forced onto packed-f32 VOP3P via
// inline asm (v_pk_fma_f32/v_pk_add_f32/v_pk_mul_f32 with neg modifiers).
// Evidence packing never formed from ext_vector C: R5 scalar=560 inst/iter ->
// R6 v2=473 (-16% only, should be ~-45%); no v_pk_max_f32 exists, and the 25
// elementwise_max sites scalarize their neighborhoods. Scalar residue kept:
// 2x v_max_f32 per dual row, ~31 DPP lane shifts, TC/eq96 uniform chains.
// Associations equal or fma-fused vs R9 (tolerance-proven headroom).
// Power iteration (10 iters) keeps the plain-C path.
//
// Lane layout: lane l holds t=2l (.x) and t=2l+1 (.y), l<48. All K/K^T
// couplings are t-offsets +-1..3 => same-lane or 1-2 lane DPP shifts.
// Row-existence masks folded into per-row sigma multipliers; lanes >=48 and
// nonexistent rows carry exact zeros so shift edges read natural zeros.

#define NITER 400
#define PITER 10

typedef float v2 __attribute__((ext_vector_type(2)));

// ---- packed f32 VOP3P (full-rate on CDNA; no literal operands allowed,
// all constants pre-broadcast into VGPR pairs) ----
__device__ __forceinline__ v2 pk_add(v2 a, v2 b) {
  v2 d; asm("v_pk_add_f32 %0, %1, %2" : "=v"(d) : "v"(a), "v"(b)); return d;
}
__device__ __forceinline__ v2 pk_sub(v2 a, v2 b) {  // a - b
  v2 d; asm("v_pk_add_f32 %0, %1, %2 neg_lo:[0,1] neg_hi:[0,1]" : "=v"(d) : "v"(a), "v"(b)); return d;
}
__device__ __forceinline__ v2 pk_fma(v2 a, v2 b, v2 c) {  // a*b + c
  v2 d; asm("v_pk_fma_f32 %0, %1, %2, %3" : "=v"(d) : "v"(a), "v"(b), "v"(c)); return d;
}
__device__ __forceinline__ v2 pk_fma_nc(v2 a, v2 b, v2 c) {  // a*b - c
  v2 d; asm("v_pk_fma_f32 %0, %1, %2, %3 neg_lo:[0,0,1] neg_hi:[0,0,1]" : "=v"(d) : "v"(a), "v"(b), "v"(c)); return d;
}
__device__ __forceinline__ v2 max0(v2 a) {  // no v_pk_max_f32 exists: 2 scalar
  v2 r; r.x = fmaxf(a.x, 0.f); r.y = fmaxf(a.y, 0.f); return r;
}

// ---- DPP lane shifts (wave modes; HW-verified R1/R5). ----
__device__ __forceinline__ float dpp_shr1(float x) {  // dst[i] = src[i-1], lane0 -> 0
  return __int_as_float(__builtin_amdgcn_update_dpp(
      0, __float_as_int(x), 0x138, 0xf, 0xf, true));   // wave_shr:1
}
__device__ __forceinline__ float dpp_shl1(float x) {  // dst[i] = src[i+1], lane63 -> 0
  return __int_as_float(__builtin_amdgcn_update_dpp(
      0, __float_as_int(x), 0x130, 0xf, 0xf, true));   // wave_shl:1
}
__device__ __forceinline__ float rl47(float x) {
  return __int_as_float(__builtin_amdgcn_readlane(__float_as_int(x), 47));
}

// Full wave64 sum via DPP (VALU pipe) -- HW-verified R1.
__device__ __forceinline__ float wave_sum64(float v) {
  float r = v;
  int x;
  x = __builtin_amdgcn_update_dpp(0, __float_as_int(r), 0x111, 0xf, 0xf, true);
  r += __int_as_float(x);
  x = __builtin_amdgcn_update_dpp(0, __float_as_int(r), 0x112, 0xf, 0xf, true);
  r += __int_as_float(x);
  x = __builtin_amdgcn_update_dpp(0, __float_as_int(r), 0x114, 0xf, 0xf, true);
  r += __int_as_float(x);
  x = __builtin_amdgcn_update_dpp(0, __float_as_int(r), 0x118, 0xf, 0xf, true);
  r += __int_as_float(x);
  x = __builtin_amdgcn_update_dpp(0, __float_as_int(r), 0x142, 0xa, 0xf, true);
  r += __int_as_float(x);
  x = __builtin_amdgcn_update_dpp(0, __float_as_int(r), 0x143, 0xc, 0xf, true);
  r += __int_as_float(x);
  return __int_as_float(__builtin_amdgcn_readlane(__float_as_int(r), 63));
}

__global__ __launch_bounds__(64, 1)
void lp_solve_kernel(const float* __restrict__ price, float* __restrict__ out) {
  const int lane = threadIdx.x;
  const int bi = blockIdx.x;
  const double ETA_D = sqrt(0.91);
  const float cET = (float)(-(ETA_D * 0.25));  // -ETA*DT (eq coeff on c)
  const float cDE = (float)(0.25 / ETA_D);     // DT/ETA (eq coeff on d)
  const v2 Z = {0.f, 0.f};

  const float act = (lane < 48) ? 1.f : 0.f;
  // row-existence masks packed over p (power mode); PDHG uses sigma*mask.
  const v2 m_r  = { (lane >= 1 && lane < 48) ? 1.f : 0.f, act };   // ramp t>=1
  const v2 m_sw = { act, (lane <= 46) ? 1.f : 0.f };               // sw t<=94
  const v2 m_md[3] = {
    { act,                      (lane <= 46) ? 1.f : 0.f },        // k=1: t<=94
    { (lane <= 46) ? 1.f : 0.f, (lane <= 46) ? 1.f : 0.f },        // k=2: t<=93
    { (lane <= 46) ? 1.f : 0.f, (lane <= 45) ? 1.f : 0.f }         // k=3: t<=92
  };

  // ---------------- state (all registers, p-packed) ----------------
  v2 xc = Z, xd = Z, xyc = Z, xyd = Z, xs = Z;
  v2 xbc = Z, xbd = Z, xbyc = Z, xbyd = Z, xbs = Z;
  v2 qc = Z, qd = Z;
  v2 yb[13];
#pragma unroll
  for (int i = 0; i < 13; ++i) yb[i] = Z;
  v2 ymc[3] = {Z, Z, Z}, ymd[3] = {Z, Z, Z};
  v2 yr[4] = {Z, Z, Z, Z};
  v2 sw0 = Z, sw1 = Z, yeq = Z;
  float yeq96 = 0.f, ytc = 0.f;
  v2 uc = Z, ud = Z, msc = Z, msd = Z;

  float sigv = 0.f, tauv = 0.f;
  float sa = 0.f;
  v2 sr = Z, ssw = Z, smd[3] = {Z, Z, Z};

  // ---------------- power-mode phase B (plain C; 10 iters only) ----------
  auto phaseB_pow = [&]() {
    yeq96 = rl47(xbs.y);
    ytc = 0.25f * wave_sum64(xbc.x + xbc.y);
    v2 pxc  = { dpp_shr1(xbc.y),  xbc.x };
    v2 pxd  = { dpp_shr1(xbd.y),  xbd.x };
    v2 pxs  = { dpp_shr1(xbs.y),  xbs.x };
    v2 pxyc = { dpp_shr1(xbyc.y), xbyc.x };
    v2 pxyd = { dpp_shr1(xbyd.y), xbyd.x };
    float a1 = dpp_shl1(xbyc.x), b1 = dpp_shl1(xbyc.y), c1 = dpp_shl1(a1);
    v2 nyc1 = { xbyc.y, a1 }, nyc2 = { a1, b1 }, nyc3 = { b1, c1 };
    float a2 = dpp_shl1(xbyd.x), b2 = dpp_shl1(xbyd.y), c2 = dpp_shl1(a2);
    v2 nyd1 = { xbyd.y, a2 }, nyd2 = { a2, b2 }, nyd3 = { b2, c2 };
    yb[0] = xbc;   yb[1] = xbd;
    yb[2] = -xbc;  yb[3] = -xbd;
    yb[4] = -xbyc; yb[5] = xbyc;
    yb[6] = -xbyd; yb[7] = xbyd;
    yb[8] = -xbs;  yb[9] = xbs;
    yb[10] = xbyc + xbyd;
    yb[11] = xbc - 195.f * xbyc;
    yb[12] = xbd - 195.f * xbyd;
    v2 base_c = xbyc - pxyc, base_d = xbyd - pxyd;
    ymc[0] = m_md[0] * (base_c - nyc1); ymc[1] = m_md[1] * (base_c - nyc2);
    ymc[2] = m_md[2] * (base_c - nyc3);
    ymd[0] = m_md[0] * (base_d - nyd1); ymd[1] = m_md[1] * (base_d - nyd2);
    ymd[2] = m_md[2] * (base_d - nyd3);
    v2 dc = xbc - pxc, dd = xbd - pxd;
    yr[0] = m_r * dc; yr[1] = -m_r * dc; yr[2] = m_r * dd; yr[3] = -m_r * dd;
    sw0 = m_sw * (xbyc + nyd1); sw1 = m_sw * (xbyd + nyc1);
    yeq = act * (xbs - pxs + cET * xbc + cDE * xbd);
    uc = yr[0] - yr[1]; ud = yr[2] - yr[3];
    msc = ymc[0] + ymc[1] + ymc[2]; msd = ymd[0] + ymd[1] + ymd[2];
  };

  // ---------------- generic gather (plain C; power loop only) ------------
  v2 gc, gd, gyc, gyd, gs;
  auto gather_gen = [&]() {
    v2 ucn  = { uc.y,  dpp_shl1(uc.x) };
    v2 udn  = { ud.y,  dpp_shl1(ud.x) };
    v2 mscn = { msc.y, dpp_shl1(msc.x) };
    v2 msdn = { msd.y, dpp_shl1(msd.x) };
    float tdn = dpp_shl1(yeq.x);
    v2 eqn = { yeq.y, (lane == 47) ? -yeq96 : tdn };
    v2 sw1p = { dpp_shr1(sw1.y), sw1.x };
    v2 sw0p = { dpp_shr1(sw0.y), sw0.x };
    v2 pc1 = { dpp_shr1(ymc[0].y), ymc[0].x };
    v2 pc2 = { dpp_shr1(ymc[1].x), dpp_shr1(ymc[1].y) };
    v2 pc3 = { dpp_shr1(dpp_shr1(ymc[2].y)), dpp_shr1(ymc[2].x) };
    v2 pd1 = { dpp_shr1(ymd[0].y), ymd[0].x };
    v2 pd2 = { dpp_shr1(ymd[1].x), dpp_shr1(ymd[1].y) };
    v2 pd3 = { dpp_shr1(dpp_shr1(ymd[2].y)), dpp_shr1(ymd[2].x) };
    gc = (yb[0] - yb[2] + yb[11]) + uc - ucn + 0.25f * ytc + cET * yeq;
    gd = (yb[1] - yb[3] + yb[12]) + ud - udn + cDE * yeq;
    gyc = (-yb[4] + yb[5] + yb[10] - 195.f * yb[11])
        + sw0 + sw1p + msc - mscn - pc1 - pc2 - pc3;
    gyd = (-yb[6] + yb[7] + yb[10] - 195.f * yb[12])
        + sw1 + sw0p + msd - msdn - pd1 - pd2 - pd3;
    gs = (-yb[8] + yb[9]) + yeq - eqn;
  };

  // ================= power iteration: ||K||_2 =================
  xbc = act; xbd = act; xbyc = act; xbyd = act; xbs = act;
  float lam2 = 1.f;
  for (int pit = 0; pit < PITER; ++pit) {
    phaseB_pow();
    gather_gen();
    v2 pv = gc * gc + gd * gd + gyc * gyc + gyd * gyd + gs * gs;
    float part = (pv.x + pv.y) * act;
    lam2 = sqrtf(wave_sum64(part));
    float inv = act / lam2;
    xbc = gc * inv; xbd = gd * inv;
    xbyc = gyc * inv; xbyd = gyd * inv; xbs = gs * inv;
  }
  tauv = (float)(0.9 / sqrt((double)lam2));
  sigv = tauv;
  sa = sigv * act;
  sr = sigv * m_r;
  ssw = sigv * m_sw;
#pragma unroll
  for (int k = 0; k < 3; ++k) smd[k] = sigv * m_md[k];

  // loop-invariant broadcast constants for the VOP3P path
  const v2 saV  = { sa, sa },  nsaV = { -sa, -sa };
  const v2 nsrV = Z - sr;
  const v2 K195 = { 195.f, 195.f }, nK195 = { -195.f, -195.f };
  const v2 K1   = { 1.f, 1.f },     K65   = { 65.f, 65.f };
  const v2 K800 = { 800.f, 800.f }, K2    = { 2.f, 2.f };
  const v2 cET2 = { cET, cET },     cDE2  = { cDE, cDE };
  const float ta = tauv * act;
  const v2 ntaV = { -ta, -ta };

  // reset all state for PDHG
#pragma unroll
  for (int i = 0; i < 13; ++i) yb[i] = Z;
#pragma unroll
  for (int k = 0; k < 3; ++k) { ymc[k] = Z; ymd[k] = Z; }
#pragma unroll
  for (int k = 0; k < 4; ++k) yr[k] = Z;
  sw0 = Z; sw1 = Z; yeq = Z;
  uc = Z; ud = Z; msc = Z; msd = Z;
  xbc = Z; xbd = Z; xbyc = Z; xbyd = Z; xbs = Z;
  xc = Z; xd = Z; xyc = Z; xyd = Z; xs = Z;
  yeq96 = 0.f; ytc = 0.f;

  // q loads (lanes >=48 nullified by ta)
  {
    const int l2 = (lane < 48) ? lane : 0;
    float p0 = price[bi * 96 + 2 * l2];
    float p1 = price[bi * 96 + 2 * l2 + 1];
    qc = (v2){ 0.25f * p0, 0.25f * p1 };
    qd = (v2){ -0.25f * p0, -0.25f * p1 };
  }

  // ================= PDHG (all-VOP3P body) =================
#pragma unroll 2
  for (int it = 0; it < NITER; ++it) {
    // ---- gather (K^T y) ----
    {
      v2 ucn  = { uc.y,  dpp_shl1(uc.x) };
      v2 udn  = { ud.y,  dpp_shl1(ud.x) };
      v2 mscn = { msc.y, dpp_shl1(msc.x) };
      v2 msdn = { msd.y, dpp_shl1(msd.x) };
      float tdn = dpp_shl1(yeq.x);
      v2 eqn = { yeq.y, (lane == 47) ? -yeq96 : tdn };
      v2 sw1p = { dpp_shr1(sw1.y), sw1.x };
      v2 sw0p = { dpp_shr1(sw0.y), sw0.x };
      v2 pc1 = { dpp_shr1(ymc[0].y), ymc[0].x };
      v2 pc2 = { dpp_shr1(ymc[1].x), dpp_shr1(ymc[1].y) };
      v2 pc3 = { dpp_shr1(dpp_shr1(ymc[2].y)), dpp_shr1(ymc[2].x) };
      v2 pd1 = { dpp_shr1(ymd[0].y), ymd[0].x };
      v2 pd2 = { dpp_shr1(ymd[1].x), dpp_shr1(ymd[1].y) };
      v2 pd3 = { dpp_shr1(dpp_shr1(ymd[2].y)), dpp_shr1(ymd[2].x) };
      float yq = 0.25f * ytc;
      v2 ytcV = { yq, yq };
      v2 t;
      t = pk_sub(yb[0], yb[2]); t = pk_add(t, yb[11]);
      t = pk_add(t, uc); t = pk_sub(t, ucn);
      t = pk_fma(cET2, yeq, t);
      gc = pk_add(t, ytcV);
      t = pk_sub(yb[1], yb[3]); t = pk_add(t, yb[12]);
      t = pk_add(t, ud); t = pk_sub(t, udn);
      gd = pk_fma(cDE2, yeq, t);
      t = pk_sub(yb[5], yb[4]); t = pk_add(t, yb[10]);
      t = pk_fma(nK195, yb[11], t);
      t = pk_add(t, sw0); t = pk_add(t, sw1p);
      t = pk_add(t, msc); t = pk_sub(t, mscn);
      t = pk_sub(t, pc1); t = pk_sub(t, pc2);
      gyc = pk_sub(t, pc3);
      t = pk_sub(yb[7], yb[6]); t = pk_add(t, yb[10]);
      t = pk_fma(nK195, yb[12], t);
      t = pk_add(t, sw1); t = pk_add(t, sw0p);
      t = pk_add(t, msd); t = pk_sub(t, msdn);
      t = pk_sub(t, pd1); t = pk_sub(t, pd2);
      gyd = pk_sub(t, pd3);
      t = pk_sub(yb[9], yb[8]); t = pk_add(t, yeq);
      gs = pk_sub(t, eqn);
    }
    // ---- x update + overrelax ----
    {
      v2 xa, t;
      t = pk_add(qc, gc); xa = pk_fma(ntaV, t, xc);
      xbc = pk_fma_nc(K2, xa, xc); xc = xa;
      t = pk_add(qd, gd); xa = pk_fma(ntaV, t, xd);
      xbd = pk_fma_nc(K2, xa, xd); xd = xa;
      xa = pk_fma(ntaV, gyc, xyc); xbyc = pk_fma_nc(K2, xa, xyc); xyc = xa;
      xa = pk_fma(ntaV, gyd, xyd); xbyd = pk_fma_nc(K2, xa, xyd); xyd = xa;
      xa = pk_fma(ntaV, gs,  xs ); xbs  = pk_fma_nc(K2, xa, xs ); xs  = xa;
    }
    // ---- dual update (K xbar, prox) ----
    {
      // wave-uniform serial chains first (overlap the row updates)
      yeq96 += sigv * rl47(xbs.y);
      float tot = wave_sum64(xbc.x + xbc.y);
      ytc = fmaxf(ytc + sigv * (0.25f * tot - 1200.f), 0.f);
      // xbar neighbor shifts
      v2 pxc  = { dpp_shr1(xbc.y),  xbc.x };
      v2 pxd  = { dpp_shr1(xbd.y),  xbd.x };
      v2 pxs  = { dpp_shr1(xbs.y),  xbs.x };
      v2 pxyc = { dpp_shr1(xbyc.y), xbyc.x };
      v2 pxyd = { dpp_shr1(xbyd.y), xbyd.x };
      float a1 = dpp_shl1(xbyc.x), b1 = dpp_shl1(xbyc.y), c1 = dpp_shl1(a1);
      v2 nyc1 = { xbyc.y, a1 }, nyc2 = { a1, b1 }, nyc3 = { b1, c1 };
      float a2 = dpp_shl1(xbyd.x), b2 = dpp_shl1(xbyd.y), c2 = dpp_shl1(a2);
      v2 nyd1 = { xbyd.y, a2 }, nyd2 = { a2, b2 }, nyd3 = { b2, c2 };
      // BOX (13 rows)
      yb[0]  = max0(pk_fma(saV, pk_sub(xbc, K195), yb[0]));
      yb[1]  = max0(pk_fma(saV, pk_sub(xbd, K195), yb[1]));
      yb[2]  = max0(pk_fma(nsaV, xbc, yb[2]));
      yb[3]  = max0(pk_fma(nsaV, xbd, yb[3]));
      yb[4]  = max0(pk_fma(nsaV, xbyc, yb[4]));
      yb[5]  = max0(pk_fma(saV, pk_sub(xbyc, K1), yb[5]));
      yb[6]  = max0(pk_fma(nsaV, xbyd, yb[6]));
      yb[7]  = max0(pk_fma(saV, pk_sub(xbyd, K1), yb[7]));
      yb[8]  = max0(pk_fma(nsaV, xbs, yb[8]));
      yb[9]  = max0(pk_fma(saV, pk_sub(xbs, K800), yb[9]));
      yb[10] = max0(pk_fma(saV, pk_sub(pk_add(xbyc, xbyd), K1), yb[10]));
      yb[11] = max0(pk_fma(saV, pk_fma(nK195, xbyc, xbc), yb[11]));
      yb[12] = max0(pk_fma(saV, pk_fma(nK195, xbyd, xbd), yb[12]));
      // MIN-DURATION
      v2 bc = pk_sub(xbyc, pxyc), bd = pk_sub(xbyd, pxyd);
      ymc[0] = max0(pk_fma(smd[0], pk_sub(bc, nyc1), ymc[0]));
      ymc[1] = max0(pk_fma(smd[1], pk_sub(bc, nyc2), ymc[1]));
      ymc[2] = max0(pk_fma(smd[2], pk_sub(bc, nyc3), ymc[2]));
      ymd[0] = max0(pk_fma(smd[0], pk_sub(bd, nyd1), ymd[0]));
      ymd[1] = max0(pk_fma(smd[1], pk_sub(bd, nyd2), ymd[1]));
      ymd[2] = max0(pk_fma(smd[2], pk_sub(bd, nyd3), ymd[2]));
      // RAMP
      v2 dc = pk_sub(xbc, pxc), dd = pk_sub(xbd, pxd);
      yr[0] = max0(pk_fma(sr,   pk_sub(dc, K65), yr[0]));
      yr[1] = max0(pk_fma(nsrV, pk_add(dc, K65), yr[1]));
      yr[2] = max0(pk_fma(sr,   pk_sub(dd, K65), yr[2]));
      yr[3] = max0(pk_fma(nsrV, pk_add(dd, K65), yr[3]));
      // SWITCH
      sw0 = max0(pk_fma(ssw, pk_sub(pk_add(xbyc, nyd1), K1), sw0));
      sw1 = max0(pk_fma(ssw, pk_sub(pk_add(xbyd, nyc1), K1), sw1));
      // EQUALITY (free dual)
      v2 de = pk_fma(cDE2, xbd, pk_fma(cET2, xbc, pk_sub(xbs, pxs)));
      yeq = pk_fma(saV, de, yeq);
      // combos for next gather
      uc = pk_sub(yr[0], yr[1]); ud = pk_sub(yr[2], yr[3]);
      msc = pk_add(pk_add(ymc[0], ymc[1]), ymc[2]);
      msd = pk_add(pk_add(ymd[0], ymd[1]), ymd[2]);
    }
  }

  // output: c then d, each (256,96)
  if (lane < 48) {
    out[bi * 96 + 2 * lane]             = xc.x;
    out[bi * 96 + 2 * lane + 1]         = xc.y;
    out[24576 + bi * 96 + 2 * lane]     = xd.x;
    out[24576 + bi * 96 + 2 * lane + 1] = xd.y;
  }
}

extern "C" void kernel_launch(void* const* d_in, const int* in_sizes, int n_in,
                              void* d_out, int out_size, void* d_ws, size_t ws_size,
                              hipStream_t stream) {
  const float* price = (const float*)d_in[0];
  float* outp = (float*)d_out;
  hipLaunchKernelGGL(lp_solve_kernel, dim3(256), dim3(64), 0, stream, price, outp);
}

// Round 11
// 216.514 us; speedup vs baseline: 1.1756x; 1.1756x over previous
//
#include <hip/hip_runtime.h>
#include <math.h>

// DiffDispatchLP: batched (256x) PDHG, 400 iters.
// R11: revert to R9 (best, 170.5us) + unroll 4 (was 2).
// R10 post-mortem: forcing v_pk_*_f32 via inline asm REGRESSED (208us) --
// VOP3P needs aligned even VGPR pairs, and every v2 built from {comp, DPP
// result} then costs pair-assembly v_movs exceeding the packing gain. In the
// interleaved (2l,2l+1) layout, scalar f32 with free component renaming is
// the cheap form. Established structure (R1-R10):
//  - total-charge dual couples ALL 96 c-columns every iter (global sum ->
//    ytc -> every gc), so multi-wave needs a per-iter cross-wave reduction
//    (~1000cy measured R3/R7) >= the whole single-wave iteration (~1023cy).
//    Single wave per item is structurally forced.
//  - within one wave: issue-bound at ~88% of the 1-SIMD issue ceiling.
//  - unroll-2 + hoisted uniform chains (R9) filled most DPP hazard slots;
//    unroll-4 doubles the scheduler's independent-iteration window (~14KB
//    body, fits 32KB I-cache).
// Numerics identical to R9/R6.
//
// Lane layout: lane l holds t=2l (.x) and t=2l+1 (.y), l<48. All K/K^T
// couplings are t-offsets +-1..3 => same-lane or 1-2 lane DPP shifts.
// Row-existence masks folded into per-row sigma multipliers; lanes >=48 and
// nonexistent rows carry exact zeros so shift edges read natural zeros.

#define NITER 400
#define PITER 10

typedef float v2 __attribute__((ext_vector_type(2)));

// ---- DPP lane shifts (wave modes; HW-verified R1/R5). ----
__device__ __forceinline__ float dpp_shr1(float x) {  // dst[i] = src[i-1], lane0 -> 0
  return __int_as_float(__builtin_amdgcn_update_dpp(
      0, __float_as_int(x), 0x138, 0xf, 0xf, true));   // wave_shr:1
}
__device__ __forceinline__ float dpp_shl1(float x) {  // dst[i] = src[i+1], lane63 -> 0
  return __int_as_float(__builtin_amdgcn_update_dpp(
      0, __float_as_int(x), 0x130, 0xf, 0xf, true));   // wave_shl:1
}

// Full wave64 sum via DPP (VALU pipe) -- HW-verified R1.
__device__ __forceinline__ float wave_sum64(float v) {
  float r = v;
  int x;
  x = __builtin_amdgcn_update_dpp(0, __float_as_int(r), 0x111, 0xf, 0xf, true);
  r += __int_as_float(x);
  x = __builtin_amdgcn_update_dpp(0, __float_as_int(r), 0x112, 0xf, 0xf, true);
  r += __int_as_float(x);
  x = __builtin_amdgcn_update_dpp(0, __float_as_int(r), 0x114, 0xf, 0xf, true);
  r += __int_as_float(x);
  x = __builtin_amdgcn_update_dpp(0, __float_as_int(r), 0x118, 0xf, 0xf, true);
  r += __int_as_float(x);
  x = __builtin_amdgcn_update_dpp(0, __float_as_int(r), 0x142, 0xa, 0xf, true);
  r += __int_as_float(x);
  x = __builtin_amdgcn_update_dpp(0, __float_as_int(r), 0x143, 0xc, 0xf, true);
  r += __int_as_float(x);
  return __int_as_float(__builtin_amdgcn_readlane(__float_as_int(r), 63));
}

__global__ __launch_bounds__(64, 1)
void lp_solve_kernel(const float* __restrict__ price, float* __restrict__ out) {
  const int lane = threadIdx.x;
  const int bi = blockIdx.x;
  const double ETA_D = sqrt(0.91);
  const float cET = (float)(-(ETA_D * 0.25));  // -ETA*DT (eq coeff on c)
  const float cDE = (float)(0.25 / ETA_D);     // DT/ETA (eq coeff on d)
  const v2 Z = {0.f, 0.f};

  const float act = (lane < 48) ? 1.f : 0.f;
  // row-existence masks packed over p (power mode); PDHG uses sigma*mask.
  const v2 m_r  = { (lane >= 1 && lane < 48) ? 1.f : 0.f, act };   // ramp t>=1
  const v2 m_sw = { act, (lane <= 46) ? 1.f : 0.f };               // sw t<=94
  const v2 m_md[3] = {
    { act,                      (lane <= 46) ? 1.f : 0.f },        // k=1: t<=94
    { (lane <= 46) ? 1.f : 0.f, (lane <= 46) ? 1.f : 0.f },        // k=2: t<=93
    { (lane <= 46) ? 1.f : 0.f, (lane <= 45) ? 1.f : 0.f }         // k=3: t<=92
  };

  // ---------------- state (all registers, p-packed) ----------------
  v2 xc = Z, xd = Z, xyc = Z, xyd = Z, xs = Z;
  v2 xbc = Z, xbd = Z, xbyc = Z, xbyd = Z, xbs = Z;
  v2 qc = Z, qd = Z;
  v2 yb[13];
#pragma unroll
  for (int i = 0; i < 13; ++i) yb[i] = Z;
  v2 ymc[3] = {Z, Z, Z}, ymd[3] = {Z, Z, Z};
  v2 yr[4] = {Z, Z, Z, Z};
  v2 sw0 = Z, sw1 = Z, yeq = Z;
  float yeq96 = 0.f, ytc = 0.f;
  v2 uc = Z, ud = Z, msc = Z, msd = Z;

  float sigv = 0.f, tauv = 0.f;
  float sa = 0.f;                 // sigma*act (per-lane scalar, broadcast)
  v2 sr = Z, ssw = Z, smd[3] = {Z, Z, Z};

  // ---------------- phase B: row dots / dual updates ----------------
  auto phaseB = [&](bool power) {
    // wave-uniform serial chains FIRST so they overlap the dual updates
    // (they read only xbar, which phaseB never writes).
    {
      float s95 = __int_as_float(__builtin_amdgcn_readlane(__float_as_int(xbs.y), 47));
      if (power) yeq96 = s95; else yeq96 += sigv * s95;
      float tot = wave_sum64(xbc.x + xbc.y);
      if (power) ytc = 0.25f * tot;
      else ytc = fmaxf(ytc + sigv * (0.25f * tot - 1200.f), 0.f);
    }
    // xbar neighbor shifts. prev(t-1): .x needs lane-1's odd; .y same-lane even.
    v2 pxc  = { dpp_shr1(xbc.y),  xbc.x };
    v2 pxd  = { dpp_shr1(xbd.y),  xbd.x };
    v2 pxs  = { dpp_shr1(xbs.y),  xbs.x };
    v2 pxyc = { dpp_shr1(xbyc.y), xbyc.x };
    v2 pxyd = { dpp_shr1(xbyd.y), xbyd.x };
    // next(t+k): chained shl1 (lanes >=48 are exact zeros -> edge fills 0).
    float a1 = dpp_shl1(xbyc.x), b1 = dpp_shl1(xbyc.y), c1 = dpp_shl1(a1);
    v2 nyc1 = { xbyc.y, a1 };
    v2 nyc2 = { a1, b1 };
    v2 nyc3 = { b1, c1 };
    float a2 = dpp_shl1(xbyd.x), b2 = dpp_shl1(xbyd.y), c2 = dpp_shl1(a2);
    v2 nyd1 = { xbyd.y, a2 };
    v2 nyd2 = { a2, b2 };
    v2 nyd3 = { b2, c2 };

    const v2 c_ = xbc, d_ = xbd, yc_ = xbyc, yd_ = xbyd, s_ = xbs;
    // BOX (13 rows; in power mode xbar is act-masked so raw dots are 0 on l>=48)
    if (power) {
      yb[0] = c_;   yb[1] = d_;
      yb[2] = -c_;  yb[3] = -d_;
      yb[4] = -yc_; yb[5] = yc_;
      yb[6] = -yd_; yb[7] = yd_;
      yb[8] = -s_;  yb[9] = s_;
      yb[10] = yc_ + yd_;
      yb[11] = c_ - 195.f * yc_;
      yb[12] = d_ - 195.f * yd_;
    } else {
      yb[0]  = __builtin_elementwise_max(yb[0]  + sa * (c_ - 195.f), Z);
      yb[1]  = __builtin_elementwise_max(yb[1]  + sa * (d_ - 195.f), Z);
      yb[2]  = __builtin_elementwise_max(yb[2]  - sa * c_,           Z);
      yb[3]  = __builtin_elementwise_max(yb[3]  - sa * d_,           Z);
      yb[4]  = __builtin_elementwise_max(yb[4]  - sa * yc_,          Z);
      yb[5]  = __builtin_elementwise_max(yb[5]  + sa * (yc_ - 1.f),  Z);
      yb[6]  = __builtin_elementwise_max(yb[6]  - sa * yd_,          Z);
      yb[7]  = __builtin_elementwise_max(yb[7]  + sa * (yd_ - 1.f),  Z);
      yb[8]  = __builtin_elementwise_max(yb[8]  - sa * s_,           Z);
      yb[9]  = __builtin_elementwise_max(yb[9]  + sa * (s_ - 800.f), Z);
      yb[10] = __builtin_elementwise_max(yb[10] + sa * (yc_ + yd_ - 1.f), Z);
      yb[11] = __builtin_elementwise_max(yb[11] + sa * (c_ - 195.f * yc_), Z);
      yb[12] = __builtin_elementwise_max(yb[12] + sa * (d_ - 195.f * yd_), Z);
    }
    // MIN-DURATION: dot(k,t) = v[t] - v[t-1] - v[t+k]
    {
      v2 base_c = yc_ - pxyc, base_d = yd_ - pxyd;
      v2 dc1 = base_c - nyc1, dc2 = base_c - nyc2, dc3 = base_c - nyc3;
      v2 dd1 = base_d - nyd1, dd2 = base_d - nyd2, dd3 = base_d - nyd3;
      if (power) {
        ymc[0] = m_md[0] * dc1; ymc[1] = m_md[1] * dc2; ymc[2] = m_md[2] * dc3;
        ymd[0] = m_md[0] * dd1; ymd[1] = m_md[1] * dd2; ymd[2] = m_md[2] * dd3;
      } else {
        ymc[0] = __builtin_elementwise_max(ymc[0] + smd[0] * dc1, Z);
        ymc[1] = __builtin_elementwise_max(ymc[1] + smd[1] * dc2, Z);
        ymc[2] = __builtin_elementwise_max(ymc[2] + smd[2] * dc3, Z);
        ymd[0] = __builtin_elementwise_max(ymd[0] + smd[0] * dd1, Z);
        ymd[1] = __builtin_elementwise_max(ymd[1] + smd[1] * dd2, Z);
        ymd[2] = __builtin_elementwise_max(ymd[2] + smd[2] * dd3, Z);
      }
    }
    // RAMP
    {
      v2 dc = c_ - pxc, dd = d_ - pxd;
      if (power) {
        yr[0] = m_r * dc; yr[1] = -m_r * dc;
        yr[2] = m_r * dd; yr[3] = -m_r * dd;
      } else {
        yr[0] = __builtin_elementwise_max(yr[0] + sr * (dc - 65.f),  Z);
        yr[1] = __builtin_elementwise_max(yr[1] + sr * (-dc - 65.f), Z);
        yr[2] = __builtin_elementwise_max(yr[2] + sr * (dd - 65.f),  Z);
        yr[3] = __builtin_elementwise_max(yr[3] + sr * (-dd - 65.f), Z);
      }
    }
    // SWITCH
    {
      v2 d0 = yc_ + nyd1, d1 = yd_ + nyc1;
      if (power) { sw0 = m_sw * d0; sw1 = m_sw * d1; }
      else {
        sw0 = __builtin_elementwise_max(sw0 + ssw * (d0 - 1.f), Z);
        sw1 = __builtin_elementwise_max(sw1 + ssw * (d1 - 1.f), Z);
      }
    }
    // EQUALITY (free dual)
    {
      v2 de = s_ - pxs + cET * c_ + cDE * d_;
      if (power) yeq = act * de;
      else yeq += sa * de;
    }
    // combos consumed by next gather (masked-zero rows keep these exact)
    uc = yr[0] - yr[1];
    ud = yr[2] - yr[3];
    msc = ymc[0] + ymc[1] + ymc[2];
    msd = ymd[0] + ymd[1] + ymd[2];
  };

  // ---------------- phase A: K^T y gather, all 10 column-chunks ----------------
  v2 gc, gd, gyc, gyd, gs;
  auto gather = [&]() {
    v2 ucn  = { uc.y,  dpp_shl1(uc.x) };
    v2 udn  = { ud.y,  dpp_shl1(ud.x) };
    v2 mscn = { msc.y, dpp_shl1(msc.x) };
    v2 msdn = { msd.y, dpp_shl1(msd.x) };
    float tdn = dpp_shl1(yeq.x);
    v2 eqn = { yeq.y, (lane == 47) ? -yeq96 : tdn };
    v2 sw1p = { dpp_shr1(sw1.y), sw1.x };
    v2 sw0p = { dpp_shr1(sw0.y), sw0.x };
    v2 pc1 = { dpp_shr1(ymc[0].y), ymc[0].x };
    v2 pc2 = { dpp_shr1(ymc[1].x), dpp_shr1(ymc[1].y) };
    v2 pc3 = { dpp_shr1(dpp_shr1(ymc[2].y)), dpp_shr1(ymc[2].x) };
    v2 pd1 = { dpp_shr1(ymd[0].y), ymd[0].x };
    v2 pd2 = { dpp_shr1(ymd[1].x), dpp_shr1(ymd[1].y) };
    v2 pd3 = { dpp_shr1(dpp_shr1(ymd[2].y)), dpp_shr1(ymd[2].x) };
    gc = (yb[0] - yb[2] + yb[11]) + uc - ucn + 0.25f * ytc + cET * yeq;
    gd = (yb[1] - yb[3] + yb[12]) + ud - udn + cDE * yeq;
    gyc = (-yb[4] + yb[5] + yb[10] - 195.f * yb[11])
        + sw0 + sw1p + msc - mscn - pc1 - pc2 - pc3;
    gyd = (-yb[6] + yb[7] + yb[10] - 195.f * yb[12])
        + sw1 + sw0p + msd - msdn - pd1 - pd2 - pd3;
    gs = (-yb[8] + yb[9]) + yeq - eqn;
  };

  // ================= power iteration: ||K||_2 =================
  xbc = act; xbd = act; xbyc = act; xbyd = act; xbs = act;
  float lam2 = 1.f;
  for (int pit = 0; pit < PITER; ++pit) {
    phaseB(true);
    gather();
    v2 pv = gc * gc + gd * gd + gyc * gyc + gyd * gyd + gs * gs;
    float part = (pv.x + pv.y) * act;
    lam2 = sqrtf(wave_sum64(part));
    float inv = act / lam2;
    xbc = gc * inv; xbd = gd * inv;
    xbyc = gyc * inv; xbyd = gyd * inv; xbs = gs * inv;
  }
  tauv = (float)(0.9 / sqrt((double)lam2));
  sigv = tauv;
  // sigma*mask row multipliers (loop-invariant)
  sa = sigv * act;
  sr = sigv * m_r;
  ssw = sigv * m_sw;
#pragma unroll
  for (int k = 0; k < 3; ++k) smd[k] = sigv * m_md[k];

  // reset all state for PDHG
#pragma unroll
  for (int i = 0; i < 13; ++i) yb[i] = Z;
#pragma unroll
  for (int k = 0; k < 3; ++k) { ymc[k] = Z; ymd[k] = Z; }
#pragma unroll
  for (int k = 0; k < 4; ++k) yr[k] = Z;
  sw0 = Z; sw1 = Z; yeq = Z;
  uc = Z; ud = Z; msc = Z; msd = Z;
  xbc = Z; xbd = Z; xbyc = Z; xbyd = Z; xbs = Z;
  xc = Z; xd = Z; xyc = Z; xyd = Z; xs = Z;
  yeq96 = 0.f; ytc = 0.f;

  // q loads (lanes >=48 nullified by tau*act)
  {
    const int l2 = (lane < 48) ? lane : 0;
    float p0 = price[bi * 96 + 2 * l2];
    float p1 = price[bi * 96 + 2 * l2 + 1];
    qc = (v2){ 0.25f * p0, 0.25f * p1 };
    qd = (v2){ -0.25f * p0, -0.25f * p1 };
  }

  // ================= PDHG =================
  const float ta = tauv * act;
#pragma unroll 4
  for (int it = 0; it < NITER; ++it) {
    gather();
    {
      v2 xa;
      xa = xc  - ta * (qc + gc);  xbc  = 2.f * xa - xc;  xc  = xa;
      xa = xd  - ta * (qd + gd);  xbd  = 2.f * xa - xd;  xd  = xa;
      xa = xyc - ta * gyc;        xbyc = 2.f * xa - xyc; xyc = xa;
      xa = xyd - ta * gyd;        xbyd = 2.f * xa - xyd; xyd = xa;
      xa = xs  - ta * gs;         xbs  = 2.f * xa - xs;  xs  = xa;
    }
    phaseB(false);
  }

  // output: c then d, each (256,96)
  if (lane < 48) {
    out[bi * 96 + 2 * lane]             = xc.x;
    out[bi * 96 + 2 * lane + 1]         = xc.y;
    out[24576 + bi * 96 + 2 * lane]     = xd.x;
    out[24576 + bi * 96 + 2 * lane + 1] = xd.y;
  }
}

extern "C" void kernel_launch(void* const* d_in, const int* in_sizes, int n_in,
                              void* d_out, int out_size, void* d_ws, size_t ws_size,
                              hipStream_t stream) {
  const float* price = (const float*)d_in[0];
  float* outp = (float*)d_out;
  hipLaunchKernelGGL(lp_solve_kernel, dim3(256), dim3(64), 0, stream, price, outp);
}